// Round 1
// baseline (324.145 us; speedup 1.0000x reference)
//
#include <hip/hip_runtime.h>
#include <hip/hip_fp16.h>
#include <math.h>

#define BB 2
#define CC 64
#define NN 16384
#define DD 3
#define KK 128
#define EE 262144
#define GG 3
#define PP 128           // n-chunks for spectral-forward partials
#define LL (NN/PP)       // 128 n per chunk
#define KTOT 576         // concat K: 256 interleaved cos/sin + 64 x + 64 h + 192 gradf
#define NCAP 64          // per-node edge bin capacity (Poisson(16): P(>64) ~ 1e-20)

typedef short bf16x8 __attribute__((ext_vector_type(8)));
typedef float f32x4  __attribute__((ext_vector_type(4)));

__device__ __forceinline__ short f2bf(float f) {
    unsigned u = __float_as_uint(f);
    u += 0x7FFF + ((u >> 16) & 1);          // round-to-nearest-even
    return (short)(u >> 16);
}
__device__ __forceinline__ float bf2f(unsigned short u) {
    return __uint_as_float(((unsigned)u) << 16);
}

// ---- workspace layout (float elements) ----
constexpr size_t OFF_XB   = 0;                                  // bf16 xB[b][n][64]
constexpr size_t OFF_PC   = OFF_XB   + (size_t)BB*NN*32;        // fp32 partial A_c
constexpr size_t OFF_PS   = OFF_PC   + (size_t)BB*PP*CC*KK;     // fp32 partial A_s
constexpr size_t OFF_AC   = OFF_PS   + (size_t)BB*PP*CC*KK;     // A_c[b][i][k]
constexpr size_t OFF_AS   = OFF_AC   + (size_t)BB*CC*KK;
constexpr size_t OFF_F0   = OFF_AS   + (size_t)BB*CC*KK;        // f0[b][o]
constexpr size_t OFF_CNT  = OFF_F0   + (size_t)BB*CC;           // int counts (zeroed)
constexpr size_t OFF_X0   = OFF_CNT  + (size_t)BB*NN;           // x0[b][i] (zeroed, atomic)
constexpr size_t OFF_GRB  = OFF_X0   + (size_t)BB*CC;           // bf16 gradfB[b][n][192]
constexpr size_t OFF_APAN = OFF_GRB  + (size_t)BB*NN*96;        // bf16 ApanT[b][64 o][576 k]
constexpr size_t OFF_GWXT = OFF_APAN + (size_t)BB*KTOT*CC/2;    // geo_wx^T [g][i] (fp32)
constexpr size_t OFF_BIN4 = (OFF_GWXT + (size_t)GG*CC + 3) & ~(size_t)3; // float4 bins[b][n][NCAP]

// ---- fused pre-pass ----
// blocks [0,512): transpose x -> xB bf16 [n][i]; x0 partial reduce (atomic)
// blocks [512,2560): edge binning (count + direct bin write, no rank/scan/fill)
// blocks [2560,2608): weights prep
__global__ void __launch_bounds__(256) k_pre(const float* __restrict__ x,
                                             const float* __restrict__ nwt,
                                             const int* __restrict__ edges,
                                             const float* __restrict__ egw,
                                             const float* __restrict__ W,
                                             const float* __restrict__ gw,
                                             const float* __restrict__ geo_wx,
                                             const float* __restrict__ w2,
                                             unsigned short* __restrict__ xB,
                                             float* __restrict__ x0,
                                             int* __restrict__ counts,
                                             float4* __restrict__ bin4,
                                             float* __restrict__ gwxT,
                                             short* __restrict__ ApanB) {
    int blk = blockIdx.x;
    int tid = threadIdx.x;
    __shared__ float tile[64][65];
    if (blk < BB*(NN/64)) {
        int b = blk / (NN/64);
        int n0 = (blk % (NN/64)) * 64;
        int lane = tid & 63, w = tid >> 6;
        for (int rr = 0; rr < 16; rr++) {
            int i = w*16 + rr;
            tile[i][lane] = x[((size_t)b*CC + i)*NN + n0 + lane];
        }
        float nwv = nwt[b*NN + n0 + lane];
        __syncthreads();
        for (int rr = 0; rr < 16; rr++) {           // xB[n][i] bf16, lane = i
            int nn = w*16 + rr;
            xB[((size_t)b*NN + n0 + nn)*64 + lane] = (unsigned short)f2bf(tile[lane][nn]);
        }
        // x0 partial: x0[b][i] += sum_n tile[i][n]*nw[n]  (wave shuffle reduce)
        for (int ii = 0; ii < 16; ii++) {
            int i = w*16 + ii;
            float v = tile[i][lane] * nwv;
            for (int off = 32; off > 0; off >>= 1) v += __shfl_xor(v, off);
            if (lane == 0) atomicAdd(&x0[b*CC + i], v);
        }
    } else if (blk < BB*(NN/64) + (BB*EE)/256) {
        int idx = (blk - BB*(NN/64))*256 + tid;
        int b   = idx / EE;
        int tgt = edges[(size_t)idx*2 + 0];
        int src = edges[(size_t)idx*2 + 1];
        const float* __restrict__ ew = &egw[(size_t)idx*3];
        float e0 = ew[0], e1 = ew[1], e2 = ew[2];
        int r = atomicAdd(&counts[b*NN + tgt], 1);
        if (r < NCAP)
            bin4[((size_t)b*NN + tgt)*NCAP + r] = make_float4(__int_as_float(src), e0, e1, e2);
    } else {
        int idx = (blk - (BB*(NN/64) + (BB*EE)/256))*256 + tid;
        if (idx < CC*CC) {
            int j = idx>>6, o = idx&63;
            short wv  = f2bf(W[o*CC+j]);
            short w2v = f2bf(w2[o*CC+j]);
            ApanB[((size_t)(0*CC+o))*KTOT + 256 + j] = wv;
            ApanB[((size_t)(1*CC+o))*KTOT + 256 + j] = wv;
            ApanB[((size_t)(0*CC+o))*KTOT + 320 + j] = w2v;
            ApanB[((size_t)(1*CC+o))*KTOT + 320 + j] = w2v;
        }
        if (idx < CC*CC*DD) {
            int g = idx>>6, o = idx&63;
            short gv = f2bf(gw[o*(CC*DD)+g]);
            ApanB[((size_t)(0*CC+o))*KTOT + 384 + g] = gv;
            ApanB[((size_t)(1*CC+o))*KTOT + 384 + g] = gv;
        }
        if (idx < GG*CC) { int g = idx>>6, i = idx&63; gwxT[idx] = geo_wx[i*GG+g]; }
    }
}

// ---- spectral forward partials on MFMA: A_c/A_s[b][i][k] over n-chunks ----
// stages x*nw directly from fp32 x (row-major [i][n] is coalesced) — no xwB intermediate
__global__ void __launch_bounds__(256) k_a(const float* __restrict__ x,
                                           const float* __restrict__ nwt,
                                           const float* __restrict__ nodes,
                                           const float* __restrict__ modes,
                                           float* __restrict__ pc, float* __restrict__ ps) {
    int bc = blockIdx.x;
    int b = bc / PP, chunk = bc % PP;
    int k0 = blockIdx.y * 64;
    int nbase = chunk * LL;
    int tid = threadIdx.x;
    int lane = tid & 63;
    int w = tid >> 6;
    int col = lane & 15;
    int quad = lane >> 4;

    __shared__ __align__(16) short Axw[64*136];   // [i][n] bf16
    __shared__ __align__(16) short Bc [64*136];   // [k][n] bf16 cos
    __shared__ __align__(16) short Bsn[64*136];   // [k][n] bf16 sin
    __shared__ float ndl[LL*3];

    for (int e = tid; e < LL*3; e += 256) ndl[e] = nodes[((size_t)b*NN + nbase)*3 + e];
    // stage x*nw tile: 64 i x 128 n = 2048 float4 (coalesced fp32 loads)
#pragma unroll
    for (int s = 0; s < 8; s++) {
        int e = tid + s*256;
        int i = e >> 5, seg = e & 31;
        float4 xv = *(const float4*)&x[((size_t)b*CC + i)*NN + nbase + seg*4];
        float4 wv = *(const float4*)&nwt[(size_t)b*NN + nbase + seg*4];
        unsigned lo = (unsigned)(unsigned short)f2bf(xv.x*wv.x)
                    | ((unsigned)(unsigned short)f2bf(xv.y*wv.y) << 16);
        unsigned hi = (unsigned)(unsigned short)f2bf(xv.z*wv.z)
                    | ((unsigned)(unsigned short)f2bf(xv.w*wv.w) << 16);
        *(uint2*)&Axw[i*136 + seg*4] = make_uint2(lo, hi);
    }
    __syncthreads();
    // basis tile (one trig eval per (k,n))
#pragma unroll
    for (int s = 0; s < 32; s++) {
        int e = tid + s*256;                 // 8192 = 64 k x 128 n
        int n = e & 127, kl = e >> 7;
        int k = k0 + kl;
        float t = ndl[n*3+0]*modes[k*3+0] + ndl[n*3+1]*modes[k*3+1]
                + ndl[n*3+2]*modes[k*3+2];
        Bc [kl*136 + n] = f2bf(__cosf(t));
        Bsn[kl*136 + n] = f2bf(__sinf(t));
    }
    __syncthreads();

    f32x4 ac[4], as4[4];
#pragma unroll
    for (int it = 0; it < 4; it++)
#pragma unroll
        for (int r = 0; r < 4; r++) { ac[it][r] = 0.f; as4[it][r] = 0.f; }

    int rowB = (w*16 + col)*136;
#pragma unroll
    for (int ns = 0; ns < 4; ns++) {
        int koff = ns*32 + quad*8;
        bf16x8 bcf = *(bf16x8*)&Bc [rowB + koff];
        bf16x8 bsf = *(bf16x8*)&Bsn[rowB + koff];
#pragma unroll
        for (int it = 0; it < 4; it++) {
            bf16x8 af = *(bf16x8*)&Axw[(it*16 + col)*136 + koff];
            ac[it]  = __builtin_amdgcn_mfma_f32_16x16x32_bf16(af, bcf, ac[it], 0, 0, 0);
            as4[it] = __builtin_amdgcn_mfma_f32_16x16x32_bf16(af, bsf, as4[it], 0, 0, 0);
        }
    }
    int base = (b*PP + chunk)*CC;
    int kw = k0 + w*16 + col;
#pragma unroll
    for (int it = 0; it < 4; it++) {
#pragma unroll
        for (int r = 0; r < 4; r++) {
            int i = it*16 + quad*4 + r;
            pc[(size_t)(base + i)*KK + kw] = ac[it][r];
            ps[(size_t)(base + i)*KK + kw] = as4[it][r];
        }
    }
}

__global__ void k_ared(const float* __restrict__ pc, const float* __restrict__ ps,
                       float* __restrict__ Ac, float* __restrict__ As) {
    int idx = blockIdx.x*256 + threadIdx.x;
    if (idx >= BB*CC*KK) return;
    int b = idx / (CC*KK);
    int r = idx % (CC*KK);
    float sc = 0.f, ss = 0.f;
    for (int ch = 0; ch < PP; ch++) {
        size_t o = ((size_t)(b*PP + ch)*CC)*KK + r;
        sc += pc[o]; ss += ps[o];
    }
    Ac[idx] = sc; As[idx] = ss;
}

// ---- channel mix -> interleaved bf16 A-panel rows {2fc[k], -2fs[k]}, + f0 ----
__global__ void __launch_bounds__(256) k_b(const float* __restrict__ Ac, const float* __restrict__ As_,
                                           const float* __restrict__ wc, const float* __restrict__ wsw,
                                           const float* __restrict__ w0, const float* __restrict__ x0,
                                           short* __restrict__ ApanB, float* __restrict__ f0) {
    int idx = blockIdx.x;
    int b = idx / (CC*2);
    int rem = idx % (CC*2);
    int o = rem >> 1, khalf = rem & 1;
    int tid = threadIdx.x;
    int kl = tid & 63, ig = tid >> 6;
    int k = khalf*64 + kl;
    float fc = 0.f, fs = 0.f;
    for (int ii = 0; ii < 16; ii++) {
        int i = ig*16 + ii;
        float a_c = Ac[(b*CC+i)*KK + k];
        float a_s = As_[(b*CC+i)*KK + k];
        float wcc = wc[((size_t)(i*CC+o))*KK + k];
        float wss = wsw[((size_t)(i*CC+o))*KK + k];
        fc += a_c*wcc + a_s*wss;
        fs += a_c*wss - a_s*wcc;
    }
    __shared__ float rc[256], rs[256];
    __shared__ float f0s[64];
    rc[tid] = fc; rs[tid] = fs;
    if (khalf == 0 && tid < 64) f0s[tid] = x0[b*CC + tid] * w0[tid*CC + o];
    __syncthreads();
    if (ig == 0) {
        fc = rc[kl] + rc[64+kl] + rc[128+kl] + rc[192+kl];
        fs = rs[kl] + rs[64+kl] + rs[128+kl] + rs[192+kl];
        unsigned pk = (unsigned)(unsigned short)f2bf(2.f*fc)
                    | ((unsigned)(unsigned short)f2bf(-2.f*fs) << 16);
        ((unsigned*)ApanB)[((size_t)(b*CC + o))*(KTOT/2) + k] = pk;
    }
    if (khalf == 0 && tid == 0) {
        float acc = 0.f;
        for (int i = 0; i < 64; i++) acc += f0s[i];
        f0[b*CC+o] = acc;
    }
}

// ---- per-node edge accumulate -> gradfB bf16 [b][n][192] (per-node bins, no offsets) ----
__global__ void __launch_bounds__(256) k_edge(const unsigned short* __restrict__ xB,
                                              const int* __restrict__ counts,
                                              const float4* __restrict__ bin4,
                                              unsigned short* __restrict__ gradfB) {
    int blk = blockIdx.x;
    int b = blk / (NN/16);
    int n0 = (blk % (NN/16)) * 16;
    int tid = threadIdx.x;
    int lane = tid & 63;
    int w = tid >> 6;                 // 4 waves, 4 nodes each
    __shared__ float4 ebuf[16*NCAP];  // 16 KB
    __shared__ float gl[16][193];
    __shared__ int scnt[16];
    if (tid < 16) scnt[tid] = min(counts[b*NN + n0 + tid], NCAP);
    __syncthreads();
    for (int t = tid; t < 16*NCAP; t += 256) {
        int nl = t >> 6, j = t & (NCAP-1);
        if (j < scnt[nl])
            ebuf[t] = bin4[((size_t)b*NN + n0 + nl)*NCAP + j];
    }
    __syncthreads();
    const unsigned short* __restrict__ xBb = xB + (size_t)b*NN*64 + lane;

    float a0[4], a1[4], a2[4], s0[4], s1[4], s2[4];
#pragma unroll
    for (int q = 0; q < 4; q++) { a0[q]=a1[q]=a2[q]=0.f; s0[q]=s1[q]=s2[q]=0.f; }

#pragma unroll
    for (int q = 0; q < 4; q++) {
        int nl = w*4 + q;
        int cnt = scnt[nl];
#pragma unroll 4
        for (int j = 0; j < cnt; j++) {
            float4 e = ebuf[nl*NCAP + j];
            int src = __float_as_int(e.x);
            float xs = bf2f(xBb[(size_t)src*64]);
            a0[q] = fmaf(xs, e.y, a0[q]);
            a1[q] = fmaf(xs, e.z, a1[q]);
            a2[q] = fmaf(xs, e.w, a2[q]);
            s0[q] += e.y; s1[q] += e.z; s2[q] += e.w;
        }
    }
#pragma unroll
    for (int q = 0; q < 4; q++) {
        int nl = w*4 + q;
        float xtgt = bf2f(xBb[(size_t)(n0 + nl)*64]);
        gl[nl][lane*3+0] = a0[q] - xtgt*s0[q];
        gl[nl][lane*3+1] = a1[q] - xtgt*s1[q];
        gl[nl][lane*3+2] = a2[q] - xtgt*s2[q];
    }
    __syncthreads();
    for (int t = tid; t < 16*192; t += 256) {
        int nl = t / 192, g = t % 192;
        gradfB[((size_t)(b*NN + n0 + nl))*192 + g] = (unsigned short)f2bf(gl[nl][g]);
    }
}

// ---- final GEMM on MFMA bf16: out = gelu(Apan^T·B + f0), K=576, tile 64o x 64n ----
__global__ void __launch_bounds__(256) k_gemm(const unsigned short* __restrict__ xB,
                                              const float* __restrict__ nodes,
                                              const float* __restrict__ modes,
                                              const float* __restrict__ geo,
                                              const unsigned short* __restrict__ gradfB,
                                              const short* __restrict__ ApanB,
                                              const float* __restrict__ f0,
                                              const float* __restrict__ wx,
                                              const float* __restrict__ gwxT,
                                              float* __restrict__ out) {
    int blk = blockIdx.x;
    int b  = blk >> 8;
    int n0 = (blk & 255) * 64;
    int tid = threadIdx.x;
    int lane = tid & 63;
    int w = tid >> 6;                  // 0..3
    int w16 = w * 16;
    int col  = lane & 15;
    int quad = lane >> 4;              // 0..3
    int quad8 = quad * 8;
    int quad4 = quad * 4;

    __shared__ __align__(16) short As[64*72];   // [o][k] bf16
    __shared__ __align__(16) short Bs[64*72];   // [n][k] bf16
    __shared__ __align__(16) short Ws[64*72];   // wx [i][j] bf16
    __shared__ float ndl[192];
    __shared__ float geo3[192];

    for (int e = tid; e < 4096; e += 256) {
        int i = e >> 6, j = e & 63;
        Ws[i*72 + j] = f2bf(wx[i*64 + j]);
    }
    if (tid < 192) ndl[tid]  = nodes[((size_t)b*NN + n0)*3 + tid];
    if (tid < 192) geo3[tid] = geo[((size_t)b*GG + (tid >> 6))*NN + n0 + (tid & 63)];

    f32x4 acc[4], xwa[4];
    float f0v[4];
#pragma unroll
    for (int r = 0; r < 4; r++) f0v[r] = f0[b*CC + w16 + quad4 + r];
#pragma unroll
    for (int nt = 0; nt < 4; nt++) {
#pragma unroll
        for (int r = 0; r < 4; r++) { acc[nt][r] = f0v[r]; xwa[nt][r] = 0.f; }
    }

    const short* __restrict__ Ab = ApanB + ((size_t)b*CC)*KTOT;

    for (int c = 0; c < 9; c++) {
        __syncthreads();
        // A chunk: 16B vector copies
        for (int e = tid; e < 512; e += 256) {
            int o = e >> 3, seg = e & 7;
            *(uint4*)&As[o*72 + seg*8] =
                *(const uint4*)&Ab[(size_t)o*KTOT + c*64 + seg*8];
        }
        // B chunk
        if (c < 4) {
#pragma unroll
            for (int s = 0; s < 8; s++) {
                int e = tid + s*256;
                int n = e >> 5, kpl = e & 31;
                int kp = c*32 + kpl;
                float t = ndl[n*3+0]*modes[kp*3+0] + ndl[n*3+1]*modes[kp*3+1]
                        + ndl[n*3+2]*modes[kp*3+2];
                unsigned pk = (unsigned)(unsigned short)f2bf(__cosf(t))
                            | ((unsigned)(unsigned short)f2bf(__sinf(t)) << 16);
                ((unsigned*)Bs)[n*36 + kpl] = pk;
            }
        } else if (c == 4) {
            // x tile: vector copy from bf16 xB[n][i]
            for (int e = tid; e < 512; e += 256) {
                int n = e >> 3, seg = e & 7;
                *(uint4*)&Bs[n*72 + seg*8] =
                    *(const uint4*)&xB[((size_t)(b*NN + n0 + n))*64 + seg*8];
            }
        } else if (c == 5) {
            // h tile from xwa (MFMA D-layout)
#pragma unroll
            for (int r = 0; r < 4; r++) {
                int i = w16 + quad4 + r;
                float g0 = gwxT[i], g1 = gwxT[64+i], g2 = gwxT[128+i];
#pragma unroll
                for (int nt = 0; nt < 4; nt++) {
                    int n = nt*16 + col;
                    float t = g0*geo3[n] + g1*geo3[64+n] + g2*geo3[128+n];
                    float ssv = t / (1.f + fabsf(t));
                    Bs[n*72 + i] = f2bf(ssv * xwa[nt][r]);
                }
            }
        } else {
            // gradf tile: vector copy from bf16 gradfB[n][192]
            const unsigned short* __restrict__ src = gradfB + (size_t)(c-6)*64;
            for (int e = tid; e < 512; e += 256) {
                int n = e >> 3, seg = e & 7;
                *(uint4*)&Bs[n*72 + seg*8] =
                    *(const uint4*)&src[((size_t)(b*NN + n0 + n))*192 + seg*8];
            }
        }
        __syncthreads();
        int rowA = (w16 + col) * 72;
#pragma unroll
        for (int ko = 0; ko < 2; ko++) {
            int koff = ko*32 + quad8;
            bf16x8 af = *(bf16x8*)&As[rowA + koff];
            if (c == 4) {
                bf16x8 wf = *(bf16x8*)&Ws[rowA + koff];
#pragma unroll
                for (int nt = 0; nt < 4; nt++) {
                    bf16x8 bfv = *(bf16x8*)&Bs[(nt*16 + col)*72 + koff];
                    acc[nt] = __builtin_amdgcn_mfma_f32_16x16x32_bf16(af, bfv, acc[nt], 0, 0, 0);
                    xwa[nt] = __builtin_amdgcn_mfma_f32_16x16x32_bf16(wf, bfv, xwa[nt], 0, 0, 0);
                }
            } else {
#pragma unroll
                for (int nt = 0; nt < 4; nt++) {
                    bf16x8 bfv = *(bf16x8*)&Bs[(nt*16 + col)*72 + koff];
                    acc[nt] = __builtin_amdgcn_mfma_f32_16x16x32_bf16(af, bfv, acc[nt], 0, 0, 0);
                }
            }
        }
    }
#pragma unroll
    for (int nt = 0; nt < 4; nt++) {
#pragma unroll
        for (int r = 0; r < 4; r++) {
            int o = w16 + quad4 + r;
            float v = acc[nt][r];
            float g = 0.5f * v * (1.f + erff(v * 0.70710678118654752f));
            out[((size_t)b*CC + o)*NN + n0 + nt*16 + col] = g;
        }
    }
}

extern "C" void kernel_launch(void* const* d_in, const int* in_sizes, int n_in,
                              void* d_out, int out_size, void* d_ws, size_t ws_size,
                              hipStream_t stream) {
    const float* x      = (const float*)d_in[0];
    const float* nodes  = (const float*)d_in[1];
    const float* nwt    = (const float*)d_in[2];
    const float* geo    = (const float*)d_in[3];
    const int*   edges  = (const int*)d_in[4];
    const float* egw    = (const float*)d_in[5];
    const float* modes  = (const float*)d_in[6];
    const float* wc     = (const float*)d_in[7];
    const float* wsw    = (const float*)d_in[8];
    const float* w0     = (const float*)d_in[9];
    const float* W      = (const float*)d_in[10];
    const float* gw     = (const float*)d_in[11];
    const float* geo_wx = (const float*)d_in[12];
    const float* wx     = (const float*)d_in[13];
    const float* w2     = (const float*)d_in[14];

    float* ws   = (float*)d_ws;
    unsigned short* xB  = (unsigned short*)(ws + OFF_XB);
    float* pc   = ws + OFF_PC;
    float* ps   = ws + OFF_PS;
    float* Ac   = ws + OFF_AC;
    float* As_  = ws + OFF_AS;
    float* f0   = ws + OFF_F0;
    int*  counts = (int*)(ws + OFF_CNT);
    float* x0   = ws + OFF_X0;
    unsigned short* gradfB = (unsigned short*)(ws + OFF_GRB);
    short* ApanB  = (short*)(ws + OFF_APAN);
    float* gwxT   = ws + OFF_GWXT;
    float4* bin4  = (float4*)(ws + OFF_BIN4);
    float* out  = (float*)d_out;

    // zero counts + x0 (contiguous) in one memset
    hipMemsetAsync(counts, 0, (size_t)(BB*NN + BB*CC)*sizeof(int), stream);

    int npre = BB*(NN/64) + (BB*EE)/256 + 48;
    k_pre  <<<npre, 256, 0, stream>>>(x, nwt, edges, egw, W, gw, geo_wx, w2,
                                      xB, x0, counts, bin4, gwxT, ApanB);
    k_a    <<<dim3(BB*PP, 2), 256, 0, stream>>>(x, nwt, nodes, modes, pc, ps);
    k_ared <<<(BB*CC*KK)/256, 256, 0, stream>>>(pc, ps, Ac, As_);
    k_b    <<<BB*CC*2, 256, 0, stream>>>(Ac, As_, wc, wsw, w0, x0, ApanB, f0);
    k_edge <<<BB*(NN/16), 256, 0, stream>>>(xB, counts, bin4, gradfB);
    k_gemm <<<BB*(NN/64), 256, 0, stream>>>(xB, nodes, modes, geo, gradfB, ApanB, f0,
                                            wx, gwxT, out);
}

// Round 2
// 212.822 us; speedup vs baseline: 1.5231x; 1.5231x over previous
//
#include <hip/hip_runtime.h>
#include <hip/hip_fp16.h>
#include <math.h>

#define BB 2
#define CC 64
#define NN 16384
#define DD 3
#define KK 128
#define EE 262144
#define GG 3
#define PP 128           // n-chunks for spectral-forward partials
#define LL (NN/PP)       // 128 n per chunk
#define KTOT 576         // concat K: 256 interleaved cos/sin + 64 x + 64 h + 192 gradf

typedef short bf16x8 __attribute__((ext_vector_type(8)));
typedef float f32x4  __attribute__((ext_vector_type(4)));

__device__ __forceinline__ short f2bf(float f) {
    unsigned u = __float_as_uint(f);
    u += 0x7FFF + ((u >> 16) & 1);          // round-to-nearest-even
    return (short)(u >> 16);
}
__device__ __forceinline__ float bf2f(unsigned short u) {
    return __uint_as_float(((unsigned)u) << 16);
}

// ---- workspace layout (float elements) ----
constexpr size_t OFF_XB   = 0;                                  // bf16 xB[b][n][64]
constexpr size_t OFF_PC   = OFF_XB   + (size_t)BB*NN*32;        // fp32 partial A_c
constexpr size_t OFF_PS   = OFF_PC   + (size_t)BB*PP*CC*KK;     // fp32 partial A_s
constexpr size_t OFF_BIN4 = OFF_PC;                             // float4 binlist[b][E] (aliases pc)
constexpr size_t OFF_AC   = OFF_PS   + (size_t)BB*PP*CC*KK;     // A_c[b][i][k]
constexpr size_t OFF_AS   = OFF_AC   + (size_t)BB*CC*KK;
constexpr size_t OFF_F0   = OFF_AS   + (size_t)BB*CC*KK;        // f0[b][o]
constexpr size_t OFF_X0   = OFF_F0   + (size_t)BB*CC;           // x0[b][i]
constexpr size_t OFF_CNT  = OFF_X0   + (size_t)BB*CC;           // int counts (zeroed)
constexpr size_t OFF_OFFS = OFF_CNT  + (size_t)BB*NN;           // int offsets
constexpr size_t OFF_RANK = OFF_OFFS + (size_t)BB*NN;           // int rank[b][E]
constexpr size_t OFF_GRB  = OFF_RANK + (size_t)BB*EE;           // bf16 gradfB[b][n][192]
constexpr size_t OFF_APAN = OFF_GRB  + (size_t)BB*NN*96;        // bf16 ApanT[b][64 o][576 k]
constexpr size_t OFF_GWXT = OFF_APAN + (size_t)BB*KTOT*CC/2;    // geo_wx^T [g][i] (fp32)

// ---- fused pre-pass ----
// blocks [0,512): transpose x -> xB bf16 [n][i]
// blocks [512,640): x0 reduction; [640,2688): edge count+rank; [2688,2736): weights prep
__global__ void __launch_bounds__(256) k_pre(const float* __restrict__ x,
                                             const float* __restrict__ nwt,
                                             const int* __restrict__ edges,
                                             const float* __restrict__ W,
                                             const float* __restrict__ gw,
                                             const float* __restrict__ geo_wx,
                                             const float* __restrict__ w2,
                                             unsigned short* __restrict__ xB,
                                             float* __restrict__ x0,
                                             int* __restrict__ counts,
                                             int* __restrict__ rank,
                                             float* __restrict__ gwxT,
                                             short* __restrict__ ApanB) {
    int blk = blockIdx.x;
    int tid = threadIdx.x;
    __shared__ float tile[64][65];
    __shared__ float red[256];
    if (blk < BB*(NN/64)) {
        int b = blk / (NN/64);
        int n0 = (blk % (NN/64)) * 64;
        int c = tid & 63, r4 = tid >> 6;
        for (int rr = 0; rr < 16; rr++) {
            int i = r4*16 + rr;
            tile[i][c] = x[((size_t)b*CC + i)*NN + n0 + c];
        }
        __syncthreads();
        for (int rr = 0; rr < 16; rr++) {           // xB[n][i] bf16, lane c = i
            int nn = r4*16 + rr;
            xB[((size_t)b*NN + n0 + nn)*64 + c] = (unsigned short)f2bf(tile[c][nn]);
        }
    } else if (blk < BB*(NN/64) + BB*CC) {
        int bi = blk - BB*(NN/64);
        int b = bi >> 6, i = bi & 63;
        const float4* __restrict__ xr = (const float4*)&x[((size_t)b*CC + i)*NN];
        const float4* __restrict__ wr = (const float4*)&nwt[(size_t)b*NN];
        float s = 0.f;
        for (int t = tid; t < NN/4; t += 256) {
            float4 xv = xr[t];
            float4 wv = wr[t];
            s += xv.x*wv.x + xv.y*wv.y + xv.z*wv.z + xv.w*wv.w;
        }
        red[tid] = s;
        __syncthreads();
        for (int off = 128; off > 0; off >>= 1) {
            if (tid < off) red[tid] += red[tid+off];
            __syncthreads();
        }
        if (tid == 0) x0[b*CC + i] = red[0];
    } else if (blk < BB*(NN/64) + BB*CC + (BB*EE)/256) {
        int idx = (blk - (BB*(NN/64) + BB*CC))*256 + tid;
        if (idx < BB*EE) {
            int tgt = edges[(size_t)idx*2 + 0];
            int b = idx / EE;
            rank[idx] = atomicAdd(&counts[b*NN + tgt], 1);
        }
    } else {
        int idx = (blk - (BB*(NN/64) + BB*CC + (BB*EE)/256))*256 + tid;
        if (idx < CC*CC) {
            int j = idx>>6, o = idx&63;
            short wv  = f2bf(W[o*CC+j]);
            short w2v = f2bf(w2[o*CC+j]);
            ApanB[((size_t)(0*CC+o))*KTOT + 256 + j] = wv;
            ApanB[((size_t)(1*CC+o))*KTOT + 256 + j] = wv;
            ApanB[((size_t)(0*CC+o))*KTOT + 320 + j] = w2v;
            ApanB[((size_t)(1*CC+o))*KTOT + 320 + j] = w2v;
        }
        if (idx < CC*CC*DD) {
            int g = idx>>6, o = idx&63;
            short gv = f2bf(gw[o*(CC*DD)+g]);
            ApanB[((size_t)(0*CC+o))*KTOT + 384 + g] = gv;
            ApanB[((size_t)(1*CC+o))*KTOT + 384 + g] = gv;
        }
        if (idx < GG*CC) { int g = idx>>6, i = idx&63; gwxT[idx] = geo_wx[i*GG+g]; }
    }
}

// ---- spectral forward partials on MFMA: A_c/A_s[b][i][k] over n-chunks ----
// stages x*nw directly from fp32 x (row-major [i][n] is coalesced) — no xwB intermediate
__global__ void __launch_bounds__(256) k_a(const float* __restrict__ x,
                                           const float* __restrict__ nwt,
                                           const float* __restrict__ nodes,
                                           const float* __restrict__ modes,
                                           float* __restrict__ pc, float* __restrict__ ps) {
    int bc = blockIdx.x;
    int b = bc / PP, chunk = bc % PP;
    int k0 = blockIdx.y * 64;
    int nbase = chunk * LL;
    int tid = threadIdx.x;
    int lane = tid & 63;
    int w = tid >> 6;
    int col = lane & 15;
    int quad = lane >> 4;

    __shared__ __align__(16) short Axw[64*136];   // [i][n] bf16
    __shared__ __align__(16) short Bc [64*136];   // [k][n] bf16 cos
    __shared__ __align__(16) short Bsn[64*136];   // [k][n] bf16 sin
    __shared__ float ndl[LL*3];

    for (int e = tid; e < LL*3; e += 256) ndl[e] = nodes[((size_t)b*NN + nbase)*3 + e];
    // stage x*nw tile: 64 i x 128 n, coalesced fp32 float4 loads, pack to bf16
#pragma unroll
    for (int s = 0; s < 8; s++) {
        int e = tid + s*256;
        int i = e >> 5, seg = e & 31;
        float4 xv = *(const float4*)&x[((size_t)b*CC + i)*NN + nbase + seg*4];
        float4 wv = *(const float4*)&nwt[(size_t)b*NN + nbase + seg*4];
        unsigned lo = (unsigned)(unsigned short)f2bf(xv.x*wv.x)
                    | ((unsigned)(unsigned short)f2bf(xv.y*wv.y) << 16);
        unsigned hi = (unsigned)(unsigned short)f2bf(xv.z*wv.z)
                    | ((unsigned)(unsigned short)f2bf(xv.w*wv.w) << 16);
        *(uint2*)&Axw[i*136 + seg*4] = make_uint2(lo, hi);
    }
    __syncthreads();
    // basis tile (one trig eval per (k,n))
#pragma unroll
    for (int s = 0; s < 32; s++) {
        int e = tid + s*256;                 // 8192 = 64 k x 128 n
        int n = e & 127, kl = e >> 7;
        int k = k0 + kl;
        float t = ndl[n*3+0]*modes[k*3+0] + ndl[n*3+1]*modes[k*3+1]
                + ndl[n*3+2]*modes[k*3+2];
        Bc [kl*136 + n] = f2bf(__cosf(t));
        Bsn[kl*136 + n] = f2bf(__sinf(t));
    }
    __syncthreads();

    f32x4 ac[4], as4[4];
#pragma unroll
    for (int it = 0; it < 4; it++)
#pragma unroll
        for (int r = 0; r < 4; r++) { ac[it][r] = 0.f; as4[it][r] = 0.f; }

    int rowB = (w*16 + col)*136;
#pragma unroll
    for (int ns = 0; ns < 4; ns++) {
        int koff = ns*32 + quad*8;
        bf16x8 bcf = *(bf16x8*)&Bc [rowB + koff];
        bf16x8 bsf = *(bf16x8*)&Bsn[rowB + koff];
#pragma unroll
        for (int it = 0; it < 4; it++) {
            bf16x8 af = *(bf16x8*)&Axw[(it*16 + col)*136 + koff];
            ac[it]  = __builtin_amdgcn_mfma_f32_16x16x32_bf16(af, bcf, ac[it], 0, 0, 0);
            as4[it] = __builtin_amdgcn_mfma_f32_16x16x32_bf16(af, bsf, as4[it], 0, 0, 0);
        }
    }
    int base = (b*PP + chunk)*CC;
    int kw = k0 + w*16 + col;
#pragma unroll
    for (int it = 0; it < 4; it++) {
#pragma unroll
        for (int r = 0; r < 4; r++) {
            int i = it*16 + quad*4 + r;
            pc[(size_t)(base + i)*KK + kw] = ac[it][r];
            ps[(size_t)(base + i)*KK + kw] = as4[it][r];
        }
    }
}

__global__ void k_ared(const float* __restrict__ pc, const float* __restrict__ ps,
                       float* __restrict__ Ac, float* __restrict__ As) {
    int idx = blockIdx.x*256 + threadIdx.x;
    if (idx >= BB*CC*KK) return;
    int b = idx / (CC*KK);
    int r = idx % (CC*KK);
    float sc = 0.f, ss = 0.f;
    for (int ch = 0; ch < PP; ch++) {
        size_t o = ((size_t)(b*PP + ch)*CC)*KK + r;
        sc += pc[o]; ss += ps[o];
    }
    Ac[idx] = sc; As[idx] = ss;
}

// ---- channel mix -> interleaved bf16 A-panel rows {2fc[k], -2fs[k]}, + f0 ----
// extra BB blocks at the end: exclusive-scan counts -> offsets (folded former k_scan)
__global__ void __launch_bounds__(256) k_b(const float* __restrict__ Ac, const float* __restrict__ As_,
                                           const float* __restrict__ wc, const float* __restrict__ wsw,
                                           const float* __restrict__ w0, const float* __restrict__ x0,
                                           const int* __restrict__ counts,
                                           int* __restrict__ offsets,
                                           short* __restrict__ ApanB, float* __restrict__ f0) {
    int idx = blockIdx.x;
    int tid = threadIdx.x;
    if (idx >= BB*CC*2) {
        // ---- scan block: offsets[b][:] = exclusive prefix sum of counts[b][:] ----
        int b = idx - BB*CC*2;
        __shared__ int part[256];
        int base = b*NN + tid*64;
        int s = 0;
        for (int j = 0; j < 64; j++) s += counts[base + j];
        part[tid] = s;
        __syncthreads();
        for (int off = 1; off < 256; off <<= 1) {
            int v = (tid >= off) ? part[tid - off] : 0;
            __syncthreads();
            part[tid] += v;
            __syncthreads();
        }
        int excl = part[tid] - s;
        for (int j = 0; j < 64; j++) {
            int c = counts[base + j];
            offsets[base + j] = excl;
            excl += c;
        }
        return;
    }
    int b = idx / (CC*2);
    int rem = idx % (CC*2);
    int o = rem >> 1, khalf = rem & 1;
    int kl = tid & 63, ig = tid >> 6;
    int k = khalf*64 + kl;
    float fc = 0.f, fs = 0.f;
    for (int ii = 0; ii < 16; ii++) {
        int i = ig*16 + ii;
        float a_c = Ac[(b*CC+i)*KK + k];
        float a_s = As_[(b*CC+i)*KK + k];
        float wcc = wc[((size_t)(i*CC+o))*KK + k];
        float wss = wsw[((size_t)(i*CC+o))*KK + k];
        fc += a_c*wcc + a_s*wss;
        fs += a_c*wss - a_s*wcc;
    }
    __shared__ float rc[256], rs[256];
    __shared__ float f0s[64];
    rc[tid] = fc; rs[tid] = fs;
    if (khalf == 0 && tid < 64) f0s[tid] = x0[b*CC + tid] * w0[tid*CC + o];
    __syncthreads();
    if (ig == 0) {
        fc = rc[kl] + rc[64+kl] + rc[128+kl] + rc[192+kl];
        fs = rs[kl] + rs[64+kl] + rs[128+kl] + rs[192+kl];
        unsigned pk = (unsigned)(unsigned short)f2bf(2.f*fc)
                    | ((unsigned)(unsigned short)f2bf(-2.f*fs) << 16);
        ((unsigned*)ApanB)[((size_t)(b*CC + o))*(KTOT/2) + k] = pk;
    }
    if (khalf == 0 && tid == 0) {
        float acc = 0.f;
        for (int i = 0; i < 64; i++) acc += f0s[i];
        f0[b*CC+o] = acc;
    }
}

// ---- fill bins (atomic-free: rank precomputed in k_pre; dense [b][E] region) ----
__global__ void k_fill(const int* __restrict__ edges, const float* __restrict__ egw,
                       const int* __restrict__ offs, const int* __restrict__ rank,
                       float4* __restrict__ bin4) {
    int idx = blockIdx.x*256 + threadIdx.x;
    if (idx >= BB*EE) return;
    int b = idx / EE;
    int tgt = edges[(size_t)idx*2+0];
    int src = edges[(size_t)idx*2+1];
    const float* __restrict__ ew = &egw[(size_t)idx*3];
    float w0 = ew[0], w1 = ew[1], w2 = ew[2];
    int pos = offs[b*NN+tgt] + rank[idx];
    bin4[(size_t)b*EE + pos] = make_float4(__int_as_float(src), w0, w1, w2);
}

// ---- per-node edge accumulate -> gradfB bf16 [b][n][192] ----
#define ECAP 1024
__global__ void __launch_bounds__(256) k_edge(const unsigned short* __restrict__ xB,
                                              const int* __restrict__ offsets,
                                              const float4* __restrict__ bin4,
                                              unsigned short* __restrict__ gradfB) {
    int blk = blockIdx.x;
    int b = blk / (NN/16);
    int n0 = (blk % (NN/16)) * 16;
    int tid = threadIdx.x;
    int lane = tid & 63;
    int w = tid >> 6;                 // 4 waves, 4 nodes each
    __shared__ float4 ebuf[ECAP];
    __shared__ float gl[16][193];
    __shared__ int soff[17];
    if (tid < 16) soff[tid] = offsets[b*NN + n0 + tid];
    if (tid == 16) soff[16] = (n0 + 16 < NN) ? offsets[b*NN + n0 + 16] : EE;
    __syncthreads();
    int base = soff[0];
    int end  = soff[16];
    const unsigned short* __restrict__ xBb = xB + (size_t)b*NN*64 + lane;

    float a0[4], a1[4], a2[4], s0[4], s1[4], s2[4];
#pragma unroll
    for (int q = 0; q < 4; q++) { a0[q]=a1[q]=a2[q]=0.f; s0[q]=s1[q]=s2[q]=0.f; }

    for (int cs = base; cs < end; cs += ECAP) {
        int ce = min(cs + ECAP, end);
        __syncthreads();
        for (int t = cs + tid; t < ce; t += 256)
            ebuf[t - cs] = bin4[(size_t)b*EE + t];
        __syncthreads();
#pragma unroll
        for (int q = 0; q < 4; q++) {
            int nl = w*4 + q;
            int js = max(soff[nl], cs);
            int je = min(soff[nl+1], ce);
#pragma unroll 4
            for (int j = js; j < je; j++) {
                float4 e = ebuf[j - cs];
                int src = __float_as_int(e.x);
                float xs = bf2f(xBb[(size_t)src*64]);
                a0[q] = fmaf(xs, e.y, a0[q]);
                a1[q] = fmaf(xs, e.z, a1[q]);
                a2[q] = fmaf(xs, e.w, a2[q]);
                s0[q] += e.y; s1[q] += e.z; s2[q] += e.w;
            }
        }
    }
    __syncthreads();
#pragma unroll
    for (int q = 0; q < 4; q++) {
        int nl = w*4 + q;
        float xtgt = bf2f(xBb[(size_t)(n0 + nl)*64]);
        gl[nl][lane*3+0] = a0[q] - xtgt*s0[q];
        gl[nl][lane*3+1] = a1[q] - xtgt*s1[q];
        gl[nl][lane*3+2] = a2[q] - xtgt*s2[q];
    }
    __syncthreads();
    for (int t = tid; t < 16*192; t += 256) {
        int nl = t / 192, g = t % 192;
        gradfB[((size_t)(b*NN + n0 + nl))*192 + g] = (unsigned short)f2bf(gl[nl][g]);
    }
}

// ---- final GEMM on MFMA bf16: out = gelu(Apan^T·B + f0), K=576, tile 64o x 64n ----
__global__ void __launch_bounds__(256) k_gemm(const unsigned short* __restrict__ xB,
                                              const float* __restrict__ nodes,
                                              const float* __restrict__ modes,
                                              const float* __restrict__ geo,
                                              const unsigned short* __restrict__ gradfB,
                                              const short* __restrict__ ApanB,
                                              const float* __restrict__ f0,
                                              const float* __restrict__ wx,
                                              const float* __restrict__ gwxT,
                                              float* __restrict__ out) {
    int blk = blockIdx.x;
    int b  = blk >> 8;
    int n0 = (blk & 255) * 64;
    int tid = threadIdx.x;
    int lane = tid & 63;
    int w = tid >> 6;                  // 0..3
    int w16 = w * 16;
    int col  = lane & 15;
    int quad = lane >> 4;              // 0..3
    int quad8 = quad * 8;
    int quad4 = quad * 4;

    __shared__ __align__(16) short As[64*72];   // [o][k] bf16
    __shared__ __align__(16) short Bs[64*72];   // [n][k] bf16
    __shared__ __align__(16) short Ws[64*72];   // wx [i][j] bf16
    __shared__ float ndl[192];
    __shared__ float geo3[192];

    for (int e = tid; e < 4096; e += 256) {
        int i = e >> 6, j = e & 63;
        Ws[i*72 + j] = f2bf(wx[i*64 + j]);
    }
    if (tid < 192) ndl[tid]  = nodes[((size_t)b*NN + n0)*3 + tid];
    if (tid < 192) geo3[tid] = geo[((size_t)b*GG + (tid >> 6))*NN + n0 + (tid & 63)];

    f32x4 acc[4], xwa[4];
    float f0v[4];
#pragma unroll
    for (int r = 0; r < 4; r++) f0v[r] = f0[b*CC + w16 + quad4 + r];
#pragma unroll
    for (int nt = 0; nt < 4; nt++) {
#pragma unroll
        for (int r = 0; r < 4; r++) { acc[nt][r] = f0v[r]; xwa[nt][r] = 0.f; }
    }

    const short* __restrict__ Ab = ApanB + ((size_t)b*CC)*KTOT;

    for (int c = 0; c < 9; c++) {
        __syncthreads();
        // A chunk: 16B vector copies
        for (int e = tid; e < 512; e += 256) {
            int o = e >> 3, seg = e & 7;
            *(uint4*)&As[o*72 + seg*8] =
                *(const uint4*)&Ab[(size_t)o*KTOT + c*64 + seg*8];
        }
        // B chunk
        if (c < 4) {
#pragma unroll
            for (int s = 0; s < 8; s++) {
                int e = tid + s*256;
                int n = e >> 5, kpl = e & 31;
                int kp = c*32 + kpl;
                float t = ndl[n*3+0]*modes[kp*3+0] + ndl[n*3+1]*modes[kp*3+1]
                        + ndl[n*3+2]*modes[kp*3+2];
                unsigned pk = (unsigned)(unsigned short)f2bf(__cosf(t))
                            | ((unsigned)(unsigned short)f2bf(__sinf(t)) << 16);
                ((unsigned*)Bs)[n*36 + kpl] = pk;
            }
        } else if (c == 4) {
            // x tile: vector copy from bf16 xB[n][i]
            for (int e = tid; e < 512; e += 256) {
                int n = e >> 3, seg = e & 7;
                *(uint4*)&Bs[n*72 + seg*8] =
                    *(const uint4*)&xB[((size_t)(b*NN + n0 + n))*64 + seg*8];
            }
        } else if (c == 5) {
            // h tile from xwa (MFMA D-layout)
#pragma unroll
            for (int r = 0; r < 4; r++) {
                int i = w16 + quad4 + r;
                float g0 = gwxT[i], g1 = gwxT[64+i], g2 = gwxT[128+i];
#pragma unroll
                for (int nt = 0; nt < 4; nt++) {
                    int n = nt*16 + col;
                    float t = g0*geo3[n] + g1*geo3[64+n] + g2*geo3[128+n];
                    float ssv = t / (1.f + fabsf(t));
                    Bs[n*72 + i] = f2bf(ssv * xwa[nt][r]);
                }
            }
        } else {
            // gradf tile: vector copy from bf16 gradfB[n][192]
            const unsigned short* __restrict__ src = gradfB + (size_t)(c-6)*64;
            for (int e = tid; e < 512; e += 256) {
                int n = e >> 3, seg = e & 7;
                *(uint4*)&Bs[n*72 + seg*8] =
                    *(const uint4*)&src[((size_t)(b*NN + n0 + n))*192 + seg*8];
            }
        }
        __syncthreads();
        int rowA = (w16 + col) * 72;
#pragma unroll
        for (int ko = 0; ko < 2; ko++) {
            int koff = ko*32 + quad8;
            bf16x8 af = *(bf16x8*)&As[rowA + koff];
            if (c == 4) {
                bf16x8 wf = *(bf16x8*)&Ws[rowA + koff];
#pragma unroll
                for (int nt = 0; nt < 4; nt++) {
                    bf16x8 bfv = *(bf16x8*)&Bs[(nt*16 + col)*72 + koff];
                    acc[nt] = __builtin_amdgcn_mfma_f32_16x16x32_bf16(af, bfv, acc[nt], 0, 0, 0);
                    xwa[nt] = __builtin_amdgcn_mfma_f32_16x16x32_bf16(wf, bfv, xwa[nt], 0, 0, 0);
                }
            } else {
#pragma unroll
                for (int nt = 0; nt < 4; nt++) {
                    bf16x8 bfv = *(bf16x8*)&Bs[(nt*16 + col)*72 + koff];
                    acc[nt] = __builtin_amdgcn_mfma_f32_16x16x32_bf16(af, bfv, acc[nt], 0, 0, 0);
                }
            }
        }
    }
#pragma unroll
    for (int nt = 0; nt < 4; nt++) {
#pragma unroll
        for (int r = 0; r < 4; r++) {
            int o = w16 + quad4 + r;
            float v = acc[nt][r];
            float g = 0.5f * v * (1.f + erff(v * 0.70710678118654752f));
            out[((size_t)b*CC + o)*NN + n0 + nt*16 + col] = g;
        }
    }
}

extern "C" void kernel_launch(void* const* d_in, const int* in_sizes, int n_in,
                              void* d_out, int out_size, void* d_ws, size_t ws_size,
                              hipStream_t stream) {
    const float* x      = (const float*)d_in[0];
    const float* nodes  = (const float*)d_in[1];
    const float* nwt    = (const float*)d_in[2];
    const float* geo    = (const float*)d_in[3];
    const int*   edges  = (const int*)d_in[4];
    const float* egw    = (const float*)d_in[5];
    const float* modes  = (const float*)d_in[6];
    const float* wc     = (const float*)d_in[7];
    const float* wsw    = (const float*)d_in[8];
    const float* w0     = (const float*)d_in[9];
    const float* W      = (const float*)d_in[10];
    const float* gw     = (const float*)d_in[11];
    const float* geo_wx = (const float*)d_in[12];
    const float* wx     = (const float*)d_in[13];
    const float* w2     = (const float*)d_in[14];

    float* ws   = (float*)d_ws;
    unsigned short* xB  = (unsigned short*)(ws + OFF_XB);
    float* pc   = ws + OFF_PC;
    float* ps   = ws + OFF_PS;
    float* Ac   = ws + OFF_AC;
    float* As_  = ws + OFF_AS;
    float* f0   = ws + OFF_F0;
    float* x0   = ws + OFF_X0;
    int*  counts = (int*)(ws + OFF_CNT);
    int*  offs   = (int*)(ws + OFF_OFFS);
    int*  rank   = (int*)(ws + OFF_RANK);
    float4* bin4 = (float4*)(ws + OFF_BIN4);
    unsigned short* gradfB = (unsigned short*)(ws + OFF_GRB);
    short* ApanB  = (short*)(ws + OFF_APAN);
    float* gwxT   = ws + OFF_GWXT;
    float* out  = (float*)d_out;

    hipMemsetAsync(counts, 0, (size_t)(BB*NN)*sizeof(int), stream);

    int npre = BB*(NN/64) + BB*CC + (BB*EE)/256 + 48;
    k_pre  <<<npre, 256, 0, stream>>>(x, nwt, edges, W, gw, geo_wx, w2,
                                      xB, x0, counts, rank, gwxT, ApanB);
    k_a    <<<dim3(BB*PP, 2), 256, 0, stream>>>(x, nwt, nodes, modes, pc, ps);
    k_ared <<<(BB*CC*KK)/256, 256, 0, stream>>>(pc, ps, Ac, As_);
    k_b    <<<BB*CC*2 + BB, 256, 0, stream>>>(Ac, As_, wc, wsw, w0, x0, counts, offs, ApanB, f0);
    k_fill <<<(BB*EE)/256, 256, 0, stream>>>(edges, egw, offs, rank, bin4);
    k_edge <<<BB*(NN/16), 256, 0, stream>>>(xB, offs, bin4, gradfB);
    k_gemm <<<BB*(NN/64), 256, 0, stream>>>(xB, nodes, modes, geo, gradfB, ApanB, f0,
                                            wx, gwxT, out);
}

// Round 4
// 198.265 us; speedup vs baseline: 1.6349x; 1.0734x over previous
//
#include <hip/hip_runtime.h>
#include <hip/hip_fp16.h>
#include <math.h>

#define BB 2
#define CC 64
#define NN 16384
#define DD 3
#define KK 128
#define EE 262144
#define GG 3
#define PP 128           // n-chunks for spectral-forward partials
#define LL (NN/PP)       // 128 n per chunk
#define KTOT 576         // concat K: 256 interleaved cos/sin + 64 x + 64 h + 192 gradf

typedef short bf16x8 __attribute__((ext_vector_type(8)));
typedef float f32x4  __attribute__((ext_vector_type(4)));

__device__ __forceinline__ short f2bf(float f) {
    unsigned u = __float_as_uint(f);
    u += 0x7FFF + ((u >> 16) & 1);          // round-to-nearest-even
    return (short)(u >> 16);
}
__device__ __forceinline__ float bf2f(unsigned short u) {
    return __uint_as_float(((unsigned)u) << 16);
}

// ---- workspace layout (float elements) ----
constexpr size_t OFF_XB   = 0;                                  // bf16 xB[b][n][64]
constexpr size_t OFF_PC   = OFF_XB   + (size_t)BB*NN*32;        // fp32 partial A_c
constexpr size_t OFF_PS   = OFF_PC   + (size_t)BB*PP*CC*KK;     // fp32 partial A_s
constexpr size_t OFF_BIN4 = OFF_PC;                             // float4 binlist[b][E] (aliases pc)
constexpr size_t OFF_AC   = OFF_PS   + (size_t)BB*PP*CC*KK;     // A_c[b][i][k]
constexpr size_t OFF_AS   = OFF_AC   + (size_t)BB*CC*KK;
constexpr size_t OFF_F0   = OFF_AS   + (size_t)BB*CC*KK;        // f0[b][o]
constexpr size_t OFF_X0   = OFF_F0   + (size_t)BB*CC;           // x0[b][i]
constexpr size_t OFF_CNT  = OFF_X0   + (size_t)BB*CC;           // int counts (zeroed)
constexpr size_t OFF_OFFS = OFF_CNT  + (size_t)BB*NN;           // int offsets
constexpr size_t OFF_RANK = OFF_OFFS + (size_t)BB*NN;           // int rank[b][E]
constexpr size_t OFF_GRB  = OFF_RANK + (size_t)BB*EE;           // bf16 gradfB[b][n][192]
constexpr size_t OFF_APAN = OFF_GRB  + (size_t)BB*NN*96;        // bf16 ApanT[b][64 o][576 k]
constexpr size_t OFF_GWXT = OFF_APAN + (size_t)BB*KTOT*CC/2;    // geo_wx^T [g][i] (fp32)

// ==== k1 = fused pre-pass ∪ spectral-forward MFMA partials ====
// sections by blockIdx.x:
//   [0,512):        transpose x -> xB bf16 [n][i]
//   [512,640):      x0 reduction
//   [640,2688):     edge count+rank (atomic)
//   [2688,2736):    weights prep
//   [2736,3760):    k_a partials: 1024 blocks = BB * PP chunks * 4 k-tiles(32)
#define S_A0 (BB*(NN/64))
#define S_A1 (S_A0 + BB*CC)
#define S_A2 (S_A1 + (BB*EE)/256)
#define S_A3 (S_A2 + 48)
#define S_A4 (S_A3 + BB*PP*4)
__global__ void __launch_bounds__(256) k1(const float* __restrict__ x,
                                          const float* __restrict__ nwt,
                                          const int* __restrict__ edges,
                                          const float* __restrict__ W,
                                          const float* __restrict__ gw,
                                          const float* __restrict__ geo_wx,
                                          const float* __restrict__ w2,
                                          const float* __restrict__ nodes,
                                          const float* __restrict__ modes,
                                          unsigned short* __restrict__ xB,
                                          float* __restrict__ x0,
                                          int* __restrict__ counts,
                                          int* __restrict__ rank,
                                          float* __restrict__ gwxT,
                                          short* __restrict__ ApanB,
                                          float* __restrict__ pc,
                                          float* __restrict__ ps) {
    int blk = blockIdx.x;
    int tid = threadIdx.x;
    // one shared pool, aliased per section (36352 B -> 4 blocks/CU)
    __shared__ __align__(16) char smem[36864];
    if (blk < S_A0) {
        // ---- transpose ----
        float (*tile)[65] = (float (*)[65])smem;
        int b = blk / (NN/64);
        int n0 = (blk % (NN/64)) * 64;
        int c = tid & 63, r4 = tid >> 6;
        for (int rr = 0; rr < 16; rr++) {
            int i = r4*16 + rr;
            tile[i][c] = x[((size_t)b*CC + i)*NN + n0 + c];
        }
        __syncthreads();
        for (int rr = 0; rr < 16; rr++) {           // xB[n][i] bf16, lane c = i
            int nn = r4*16 + rr;
            xB[((size_t)b*NN + n0 + nn)*64 + c] = (unsigned short)f2bf(tile[c][nn]);
        }
    } else if (blk < S_A1) {
        // ---- x0 reduction ----
        float* red = (float*)smem;
        int bi = blk - S_A0;
        int b = bi >> 6, i = bi & 63;
        const float4* __restrict__ xr = (const float4*)&x[((size_t)b*CC + i)*NN];
        const float4* __restrict__ wr = (const float4*)&nwt[(size_t)b*NN];
        float s = 0.f;
        for (int t = tid; t < NN/4; t += 256) {
            float4 xv = xr[t];
            float4 wv = wr[t];
            s += xv.x*wv.x + xv.y*wv.y + xv.z*wv.z + xv.w*wv.w;
        }
        red[tid] = s;
        __syncthreads();
        for (int off = 128; off > 0; off >>= 1) {
            if (tid < off) red[tid] += red[tid+off];
            __syncthreads();
        }
        if (tid == 0) x0[b*CC + i] = red[0];
    } else if (blk < S_A2) {
        // ---- edge count + rank ----
        int idx = (blk - S_A1)*256 + tid;
        int tgt = edges[(size_t)idx*2 + 0];
        int b = idx / EE;
        rank[idx] = atomicAdd(&counts[b*NN + tgt], 1);
    } else if (blk < S_A3) {
        // ---- weights prep ----
        int idx = (blk - S_A2)*256 + tid;
        if (idx < CC*CC) {
            int j = idx>>6, o = idx&63;
            short wv  = f2bf(W[o*CC+j]);
            short w2v = f2bf(w2[o*CC+j]);
            ApanB[((size_t)(0*CC+o))*KTOT + 256 + j] = wv;
            ApanB[((size_t)(1*CC+o))*KTOT + 256 + j] = wv;
            ApanB[((size_t)(0*CC+o))*KTOT + 320 + j] = w2v;
            ApanB[((size_t)(1*CC+o))*KTOT + 320 + j] = w2v;
        }
        if (idx < CC*CC*DD) {
            int g = idx>>6, o = idx&63;
            short gv = f2bf(gw[o*(CC*DD)+g]);
            ApanB[((size_t)(0*CC+o))*KTOT + 384 + g] = gv;
            ApanB[((size_t)(1*CC+o))*KTOT + 384 + g] = gv;
        }
        if (idx < GG*CC) { int g = idx>>6, i = idx&63; gwxT[idx] = geo_wx[i*GG+g]; }
    } else {
        // ---- spectral partials (k_a), 32-wide k-tile ----
        short* Axw = (short*)smem;                     // [64 i][136] bf16
        short* Bc  = (short*)(smem + 17408);           // [32 k][136] bf16 cos
        short* Bsn = (short*)(smem + 17408 + 8704);    // [32 k][136] bf16 sin
        float* ndl = (float*)(smem + 17408 + 8704 + 8704);  // LL*3 floats
        int bc = blk - S_A3;             // [0, 1024)
        int b = bc >> 9;
        int rem = bc & 511;
        int chunk = rem >> 2;            // [0,128)
        int kt = rem & 3;
        int k0 = kt * 32;
        int nbase = chunk * LL;
        int lane = tid & 63;
        int w = tid >> 6;
        int col = lane & 15;
        int quad = lane >> 4;
        int wk = w & 1;                  // k-block within 32-tile
        int wi = w >> 1;                 // i-half

        for (int e = tid; e < LL*3; e += 256) ndl[e] = nodes[((size_t)b*NN + nbase)*3 + e];
        // stage x*nw tile: 64 i x 128 n, coalesced fp32 float4 loads, pack bf16
#pragma unroll
        for (int s = 0; s < 8; s++) {
            int e = tid + s*256;
            int i = e >> 5, seg = e & 31;
            float4 xv = *(const float4*)&x[((size_t)b*CC + i)*NN + nbase + seg*4];
            float4 wv = *(const float4*)&nwt[(size_t)b*NN + nbase + seg*4];
            unsigned lo = (unsigned)(unsigned short)f2bf(xv.x*wv.x)
                        | ((unsigned)(unsigned short)f2bf(xv.y*wv.y) << 16);
            unsigned hi = (unsigned)(unsigned short)f2bf(xv.z*wv.z)
                        | ((unsigned)(unsigned short)f2bf(xv.w*wv.w) << 16);
            *(uint2*)&Axw[i*136 + seg*4] = make_uint2(lo, hi);
        }
        __syncthreads();
        // basis tile: 32 k x 128 n trig
#pragma unroll
        for (int s = 0; s < 16; s++) {
            int e = tid + s*256;
            int n = e & 127, kl = e >> 7;
            int k = k0 + kl;
            float t = ndl[n*3+0]*modes[k*3+0] + ndl[n*3+1]*modes[k*3+1]
                    + ndl[n*3+2]*modes[k*3+2];
            Bc [kl*136 + n] = f2bf(__cosf(t));
            Bsn[kl*136 + n] = f2bf(__sinf(t));
        }
        __syncthreads();

        f32x4 ac[2], as4[2];
#pragma unroll
        for (int it = 0; it < 2; it++)
#pragma unroll
            for (int r = 0; r < 4; r++) { ac[it][r] = 0.f; as4[it][r] = 0.f; }

        int rowB = (wk*16 + col)*136;
#pragma unroll
        for (int ns = 0; ns < 4; ns++) {
            int koff = ns*32 + quad*8;
            bf16x8 bcf = *(bf16x8*)&Bc [rowB + koff];
            bf16x8 bsf = *(bf16x8*)&Bsn[rowB + koff];
#pragma unroll
            for (int it = 0; it < 2; it++) {
                int itile = wi*2 + it;
                bf16x8 af = *(bf16x8*)&Axw[(itile*16 + col)*136 + koff];
                ac[it]  = __builtin_amdgcn_mfma_f32_16x16x32_bf16(af, bcf, ac[it], 0, 0, 0);
                as4[it] = __builtin_amdgcn_mfma_f32_16x16x32_bf16(af, bsf, as4[it], 0, 0, 0);
            }
        }
        int base = (b*PP + chunk)*CC;
        int kw = k0 + wk*16 + col;
#pragma unroll
        for (int it = 0; it < 2; it++) {
#pragma unroll
            for (int r = 0; r < 4; r++) {
                int i = (wi*2 + it)*16 + quad*4 + r;
                pc[(size_t)(base + i)*KK + kw] = ac[it][r];
                ps[(size_t)(base + i)*KK + kw] = as4[it][r];
            }
        }
    }
}

// ==== k2 = partial reduction (256 blocks, 4 thr/output) ∪ count scan (BB blocks) ====
__global__ void __launch_bounds__(256) k2(const float* __restrict__ pc, const float* __restrict__ ps,
                                          float* __restrict__ Ac, float* __restrict__ As,
                                          const int* __restrict__ counts,
                                          int* __restrict__ offsets) {
    int blk = blockIdx.x;
    int tid = threadIdx.x;
    if (blk < 256) {
        int idx = blk*64 + (tid >> 2);      // output element in [0, BB*CC*KK=16384)
        int sub = tid & 3;
        if (idx >= BB*CC*KK) return;        // guard (BUGFIX r3: was 512 blocks, OOB writes)
        int b = idx / (CC*KK);
        int r = idx % (CC*KK);
        float sc = 0.f, ss = 0.f;
        for (int ch = sub; ch < PP; ch += 4) {
            size_t o = ((size_t)(b*PP + ch)*CC)*KK + r;
            sc += pc[o]; ss += ps[o];
        }
        sc += __shfl_xor(sc, 1); sc += __shfl_xor(sc, 2);
        ss += __shfl_xor(ss, 1); ss += __shfl_xor(ss, 2);
        if (sub == 0) { Ac[idx] = sc; As[idx] = ss; }
    } else {
        // exclusive scan of counts -> offsets
        int b = blk - 256;
        __shared__ int part[256];
        int base = b*NN + tid*64;
        int s = 0;
        for (int j = 0; j < 64; j++) s += counts[base + j];
        part[tid] = s;
        __syncthreads();
        for (int off = 1; off < 256; off <<= 1) {
            int v = (tid >= off) ? part[tid - off] : 0;
            __syncthreads();
            part[tid] += v;
            __syncthreads();
        }
        int excl = part[tid] - s;
        for (int j = 0; j < 64; j++) {
            int c = counts[base + j];
            offsets[base + j] = excl;
            excl += c;
        }
    }
}

// ==== k3 = channel mix (256 blocks) ∪ bin fill (2048 blocks) ====
__global__ void __launch_bounds__(256) k3(const float* __restrict__ Ac, const float* __restrict__ As_,
                                          const float* __restrict__ wc, const float* __restrict__ wsw,
                                          const float* __restrict__ w0, const float* __restrict__ x0,
                                          const int* __restrict__ edges, const float* __restrict__ egw,
                                          const int* __restrict__ offs, const int* __restrict__ rank,
                                          float4* __restrict__ bin4,
                                          short* __restrict__ ApanB, float* __restrict__ f0) {
    int idx = blockIdx.x;
    int tid = threadIdx.x;
    if (idx >= BB*CC*2) {
        // ---- bin fill (atomic-free: rank precomputed) ----
        int e = (idx - BB*CC*2)*256 + tid;
        int b = e / EE;
        int tgt = edges[(size_t)e*2+0];
        int src = edges[(size_t)e*2+1];
        const float* __restrict__ ew = &egw[(size_t)e*3];
        float e0 = ew[0], e1 = ew[1], e2 = ew[2];
        int pos = offs[b*NN+tgt] + rank[e];
        bin4[(size_t)b*EE + pos] = make_float4(__int_as_float(src), e0, e1, e2);
        return;
    }
    int b = idx / (CC*2);
    int rem = idx % (CC*2);
    int o = rem >> 1, khalf = rem & 1;
    int kl = tid & 63, ig = tid >> 6;
    int k = khalf*64 + kl;
    float fc = 0.f, fs = 0.f;
    for (int ii = 0; ii < 16; ii++) {
        int i = ig*16 + ii;
        float a_c = Ac[(b*CC+i)*KK + k];
        float a_s = As_[(b*CC+i)*KK + k];
        float wcc = wc[((size_t)(i*CC+o))*KK + k];
        float wss = wsw[((size_t)(i*CC+o))*KK + k];
        fc += a_c*wcc + a_s*wss;
        fs += a_c*wss - a_s*wcc;
    }
    __shared__ float rc[256], rs[256];
    __shared__ float f0s[64];
    rc[tid] = fc; rs[tid] = fs;
    if (khalf == 0 && tid < 64) f0s[tid] = x0[b*CC + tid] * w0[tid*CC + o];
    __syncthreads();
    if (ig == 0) {
        fc = rc[kl] + rc[64+kl] + rc[128+kl] + rc[192+kl];
        fs = rs[kl] + rs[64+kl] + rs[128+kl] + rs[192+kl];
        unsigned pk = (unsigned)(unsigned short)f2bf(2.f*fc)
                    | ((unsigned)(unsigned short)f2bf(-2.f*fs) << 16);
        ((unsigned*)ApanB)[((size_t)(b*CC + o))*(KTOT/2) + k] = pk;
    }
    if (khalf == 0 && tid == 0) {
        float acc = 0.f;
        for (int i = 0; i < 64; i++) acc += f0s[i];
        f0[b*CC+o] = acc;
    }
}

// ---- per-node edge accumulate -> gradfB bf16 [b][n][192] ----
#define ECAP 1024
__global__ void __launch_bounds__(256) k_edge(const unsigned short* __restrict__ xB,
                                              const int* __restrict__ offsets,
                                              const float4* __restrict__ bin4,
                                              unsigned short* __restrict__ gradfB) {
    int blk = blockIdx.x;
    int b = blk / (NN/16);
    int n0 = (blk % (NN/16)) * 16;
    int tid = threadIdx.x;
    int lane = tid & 63;
    int w = tid >> 6;                 // 4 waves, 4 nodes each
    __shared__ float4 ebuf[ECAP];
    __shared__ float gl[16][193];
    __shared__ int soff[17];
    if (tid < 16) soff[tid] = offsets[b*NN + n0 + tid];
    if (tid == 16) soff[16] = (n0 + 16 < NN) ? offsets[b*NN + n0 + 16] : EE;
    __syncthreads();
    int base = soff[0];
    int end  = soff[16];
    const unsigned short* __restrict__ xBb = xB + (size_t)b*NN*64 + lane;

    float a0[4], a1[4], a2[4], s0[4], s1[4], s2[4];
#pragma unroll
    for (int q = 0; q < 4; q++) { a0[q]=a1[q]=a2[q]=0.f; s0[q]=s1[q]=s2[q]=0.f; }

    for (int cs = base; cs < end; cs += ECAP) {
        int ce = min(cs + ECAP, end);
        __syncthreads();
        for (int t = cs + tid; t < ce; t += 256)
            ebuf[t - cs] = bin4[(size_t)b*EE + t];
        __syncthreads();
#pragma unroll
        for (int q = 0; q < 4; q++) {
            int nl = w*4 + q;
            int js = max(soff[nl], cs);
            int je = min(soff[nl+1], ce);
#pragma unroll 4
            for (int j = js; j < je; j++) {
                float4 e = ebuf[j - cs];
                int src = __float_as_int(e.x);
                float xs = bf2f(xBb[(size_t)src*64]);
                a0[q] = fmaf(xs, e.y, a0[q]);
                a1[q] = fmaf(xs, e.z, a1[q]);
                a2[q] = fmaf(xs, e.w, a2[q]);
                s0[q] += e.y; s1[q] += e.z; s2[q] += e.w;
            }
        }
    }
    __syncthreads();
#pragma unroll
    for (int q = 0; q < 4; q++) {
        int nl = w*4 + q;
        float xtgt = bf2f(xBb[(size_t)(n0 + nl)*64]);
        gl[nl][lane*3+0] = a0[q] - xtgt*s0[q];
        gl[nl][lane*3+1] = a1[q] - xtgt*s1[q];
        gl[nl][lane*3+2] = a2[q] - xtgt*s2[q];
    }
    __syncthreads();
    for (int t = tid; t < 16*192; t += 256) {
        int nl = t / 192, g = t % 192;
        gradfB[((size_t)(b*NN + n0 + nl))*192 + g] = (unsigned short)f2bf(gl[nl][g]);
    }
}

// ---- final GEMM on MFMA bf16: out = gelu(Apan^T·B + f0), K=576, tile 64o x 64n ----
__global__ void __launch_bounds__(256) k_gemm(const unsigned short* __restrict__ xB,
                                              const float* __restrict__ nodes,
                                              const float* __restrict__ modes,
                                              const float* __restrict__ geo,
                                              const unsigned short* __restrict__ gradfB,
                                              const short* __restrict__ ApanB,
                                              const float* __restrict__ f0,
                                              const float* __restrict__ wx,
                                              const float* __restrict__ gwxT,
                                              float* __restrict__ out) {
    int blk = blockIdx.x;
    int b  = blk >> 8;
    int n0 = (blk & 255) * 64;
    int tid = threadIdx.x;
    int lane = tid & 63;
    int w = tid >> 6;                  // 0..3
    int w16 = w * 16;
    int col  = lane & 15;
    int quad = lane >> 4;              // 0..3
    int quad8 = quad * 8;
    int quad4 = quad * 4;

    __shared__ __align__(16) short As[64*72];   // [o][k] bf16
    __shared__ __align__(16) short Bs[64*72];   // [n][k] bf16
    __shared__ __align__(16) short Ws[64*72];   // wx [i][j] bf16
    __shared__ float ndl[192];
    __shared__ float geo3[192];

    for (int e = tid; e < 4096; e += 256) {
        int i = e >> 6, j = e & 63;
        Ws[i*72 + j] = f2bf(wx[i*64 + j]);
    }
    if (tid < 192) ndl[tid]  = nodes[((size_t)b*NN + n0)*3 + tid];
    if (tid < 192) geo3[tid] = geo[((size_t)b*GG + (tid >> 6))*NN + n0 + (tid & 63)];

    f32x4 acc[4], xwa[4];
    float f0v[4];
#pragma unroll
    for (int r = 0; r < 4; r++) f0v[r] = f0[b*CC + w16 + quad4 + r];
#pragma unroll
    for (int nt = 0; nt < 4; nt++) {
#pragma unroll
        for (int r = 0; r < 4; r++) { acc[nt][r] = f0v[r]; xwa[nt][r] = 0.f; }
    }

    const short* __restrict__ Ab = ApanB + ((size_t)b*CC)*KTOT;

    for (int c = 0; c < 9; c++) {
        __syncthreads();
        // A chunk: 16B vector copies
        for (int e = tid; e < 512; e += 256) {
            int o = e >> 3, seg = e & 7;
            *(uint4*)&As[o*72 + seg*8] =
                *(const uint4*)&Ab[(size_t)o*KTOT + c*64 + seg*8];
        }
        // B chunk
        if (c < 4) {
#pragma unroll
            for (int s = 0; s < 8; s++) {
                int e = tid + s*256;
                int n = e >> 5, kpl = e & 31;
                int kp = c*32 + kpl;
                float t = ndl[n*3+0]*modes[kp*3+0] + ndl[n*3+1]*modes[kp*3+1]
                        + ndl[n*3+2]*modes[kp*3+2];
                unsigned pk = (unsigned)(unsigned short)f2bf(__cosf(t))
                            | ((unsigned)(unsigned short)f2bf(__sinf(t)) << 16);
                ((unsigned*)Bs)[n*36 + kpl] = pk;
            }
        } else if (c == 4) {
            // x tile: vector copy from bf16 xB[n][i]
            for (int e = tid; e < 512; e += 256) {
                int n = e >> 3, seg = e & 7;
                *(uint4*)&Bs[n*72 + seg*8] =
                    *(const uint4*)&xB[((size_t)(b*NN + n0 + n))*64 + seg*8];
            }
        } else if (c == 5) {
            // h tile from xwa (MFMA D-layout)
#pragma unroll
            for (int r = 0; r < 4; r++) {
                int i = w16 + quad4 + r;
                float g0 = gwxT[i], g1 = gwxT[64+i], g2 = gwxT[128+i];
#pragma unroll
                for (int nt = 0; nt < 4; nt++) {
                    int n = nt*16 + col;
                    float t = g0*geo3[n] + g1*geo3[64+n] + g2*geo3[128+n];
                    float ssv = t / (1.f + fabsf(t));
                    Bs[n*72 + i] = f2bf(ssv * xwa[nt][r]);
                }
            }
        } else {
            // gradf tile: vector copy from bf16 gradfB[n][192]
            const unsigned short* __restrict__ src = gradfB + (size_t)(c-6)*64;
            for (int e = tid; e < 512; e += 256) {
                int n = e >> 3, seg = e & 7;
                *(uint4*)&Bs[n*72 + seg*8] =
                    *(const uint4*)&src[((size_t)(b*NN + n0 + n))*192 + seg*8];
            }
        }
        __syncthreads();
        int rowA = (w16 + col) * 72;
#pragma unroll
        for (int ko = 0; ko < 2; ko++) {
            int koff = ko*32 + quad8;
            bf16x8 af = *(bf16x8*)&As[rowA + koff];
            if (c == 4) {
                bf16x8 wf = *(bf16x8*)&Ws[rowA + koff];
#pragma unroll
                for (int nt = 0; nt < 4; nt++) {
                    bf16x8 bfv = *(bf16x8*)&Bs[(nt*16 + col)*72 + koff];
                    acc[nt] = __builtin_amdgcn_mfma_f32_16x16x32_bf16(af, bfv, acc[nt], 0, 0, 0);
                    xwa[nt] = __builtin_amdgcn_mfma_f32_16x16x32_bf16(wf, bfv, xwa[nt], 0, 0, 0);
                }
            } else {
#pragma unroll
                for (int nt = 0; nt < 4; nt++) {
                    bf16x8 bfv = *(bf16x8*)&Bs[(nt*16 + col)*72 + koff];
                    acc[nt] = __builtin_amdgcn_mfma_f32_16x16x32_bf16(af, bfv, acc[nt], 0, 0, 0);
                }
            }
        }
    }
#pragma unroll
    for (int nt = 0; nt < 4; nt++) {
#pragma unroll
        for (int r = 0; r < 4; r++) {
            int o = w16 + quad4 + r;
            float v = acc[nt][r];
            float g = 0.5f * v * (1.f + erff(v * 0.70710678118654752f));
            out[((size_t)b*CC + o)*NN + n0 + nt*16 + col] = g;
        }
    }
}

extern "C" void kernel_launch(void* const* d_in, const int* in_sizes, int n_in,
                              void* d_out, int out_size, void* d_ws, size_t ws_size,
                              hipStream_t stream) {
    const float* x      = (const float*)d_in[0];
    const float* nodes  = (const float*)d_in[1];
    const float* nwt    = (const float*)d_in[2];
    const float* geo    = (const float*)d_in[3];
    const int*   edges  = (const int*)d_in[4];
    const float* egw    = (const float*)d_in[5];
    const float* modes  = (const float*)d_in[6];
    const float* wc     = (const float*)d_in[7];
    const float* wsw    = (const float*)d_in[8];
    const float* w0     = (const float*)d_in[9];
    const float* W      = (const float*)d_in[10];
    const float* gw     = (const float*)d_in[11];
    const float* geo_wx = (const float*)d_in[12];
    const float* wx     = (const float*)d_in[13];
    const float* w2     = (const float*)d_in[14];

    float* ws   = (float*)d_ws;
    unsigned short* xB  = (unsigned short*)(ws + OFF_XB);
    float* pc   = ws + OFF_PC;
    float* ps   = ws + OFF_PS;
    float* Ac   = ws + OFF_AC;
    float* As_  = ws + OFF_AS;
    float* f0   = ws + OFF_F0;
    float* x0   = ws + OFF_X0;
    int*  counts = (int*)(ws + OFF_CNT);
    int*  offs   = (int*)(ws + OFF_OFFS);
    int*  rank   = (int*)(ws + OFF_RANK);
    float4* bin4 = (float4*)(ws + OFF_BIN4);
    unsigned short* gradfB = (unsigned short*)(ws + OFF_GRB);
    short* ApanB  = (short*)(ws + OFF_APAN);
    float* gwxT   = ws + OFF_GWXT;
    float* out  = (float*)d_out;

    hipMemsetAsync(counts, 0, (size_t)(BB*NN)*sizeof(int), stream);

    k1 <<<S_A4, 256, 0, stream>>>(x, nwt, edges, W, gw, geo_wx, w2, nodes, modes,
                                  xB, x0, counts, rank, gwxT, ApanB, pc, ps);
    k2 <<<256 + BB, 256, 0, stream>>>(pc, ps, Ac, As_, counts, offs);
    k3 <<<BB*CC*2 + (BB*EE)/256, 256, 0, stream>>>(Ac, As_, wc, wsw, w0, x0,
                                                   edges, egw, offs, rank, bin4, ApanB, f0);
    k_edge <<<BB*(NN/16), 256, 0, stream>>>(xB, offs, bin4, gradfB);
    k_gemm <<<BB*(NN/64), 256, 0, stream>>>(xB, nodes, modes, geo, gradfB, ApanB, f0,
                                            wx, gwxT, out);
}